// Round 10
// baseline (146.021 us; speedup 1.0000x reference)
//
#include <hip/hip_runtime.h>
#include <hip/hip_bf16.h>

// EvoAttn: causal self-attention with Q=K=V = x.reshape(B,L,H,D).
// B=2 H=16 L=2048 D=128, fp32 in/out, bf16 MFMA compute.
// v10: 32x32x16 MFMA, 4 waves = (qhalf,ksplit) each 32q x 32k per step,
//      P kept in registers via cvt_pk_bf16 + permlane32_swap (no P LDS),
//      K/V double-buffered fragment-order tiles, 1 barrier/step,
//      per-segment (m,l,O) merge across the k-split wave pair.

#define TL 2048
#define TE 2048
#define TD 128
#define KB 64
#define NTILES 32                          // TL / KB
#define TILE_B 16384                       // 64*128*2 bytes
#define KV_REGION (32 * NTILES * TILE_B)   // 16 MB per layout
#define WS_NEED (2u * (unsigned)KV_REGION) // 32 MB

typedef __attribute__((ext_vector_type(8))) short bf16x8;
typedef __attribute__((ext_vector_type(4))) float f32x4;
typedef __attribute__((ext_vector_type(16))) float f32x16;
typedef __attribute__((ext_vector_type(8))) unsigned short u16x8;
typedef __attribute__((ext_vector_type(4))) unsigned short u16x4;
typedef __attribute__((ext_vector_type(2))) unsigned int u32x2;
typedef __attribute__((ext_vector_type(4))) unsigned int u32x4;

// (1/sqrt(128)) * log2(e)
#define SCALE_LOG2E 0.12751879f

__device__ __forceinline__ unsigned short f2bf(float f) {
  __hip_bfloat16 h = __float2bfloat16(f);
  return __builtin_bit_cast(unsigned short, h);
}

__device__ __forceinline__ f32x4 mfma16(bf16x8 a, bf16x8 b, f32x4 c) {
  return __builtin_amdgcn_mfma_f32_16x16x32_bf16(a, b, c, 0, 0, 0);
}
__device__ __forceinline__ f32x16 mfma32(bf16x8 a, bf16x8 b, f32x16 c) {
  return __builtin_amdgcn_mfma_f32_32x32x16_bf16(a, b, c, 0, 0, 0);
}

__device__ __forceinline__ void gl_lds16(const void* g, void* l) {
  __builtin_amdgcn_global_load_lds(
      (__attribute__((address_space(1))) void*)(g),
      (__attribute__((address_space(3))) void*)(l), 16, 0, 0);
}

__device__ __forceinline__ unsigned cvtpk(float lo, float hi) {
  unsigned r;
  asm("v_cvt_pk_bf16_f32 %0, %1, %2" : "=v"(r) : "v"(lo), "v"(hi));
  return r;
}

// ws layout (per tile bid = bh*32 + kt):
// K region: 16B unit (ks,dseg,hi,k31) at ((ks*8+dseg)*64 + hi*32 + k31)*16
//   holding K[ks*32+k31][dseg*16+hi*8+j], j=0..7.  (32x32x16 A-operand order)
// V region: 16B unit (ks,kc,dtile,hi,d31) at (((ks*2+kc)*4+dtile)*64+hi*32+d31)*16
//   holding V[ks*32+kc*16+hi*8+j][dtile*32+d31].   (32x32x16 B-operand order)
__global__ void __launch_bounds__(256)
prepack(const float* __restrict__ x, char* __restrict__ wsb) {
  const int bid = blockIdx.x;            // bh*32 + kt
  const int kt = bid & 31;
  const int bh = bid >> 5;
  const int b = bh >> 4;
  const int h = bh & 15;
  const float* src = x + (size_t)b * TL * TE + h * TD + (size_t)kt * KB * TE;
  const int t = threadIdx.x;
  const int kr = (t >> 4) << 2;          // 4 consecutive k-rows
  const int d0 = (t & 15) << 3;          // 8 d-cols
  unsigned short c[4][8];
#pragma unroll
  for (int rr = 0; rr < 4; ++rr) {
    const float* p = src + (kr + rr) * TE + d0;
    const float4 a = *(const float4*)p;
    const float4 bb = *(const float4*)(p + 4);
    c[rr][0] = f2bf(a.x);  c[rr][1] = f2bf(a.y);  c[rr][2] = f2bf(a.z);  c[rr][3] = f2bf(a.w);
    c[rr][4] = f2bf(bb.x); c[rr][5] = f2bf(bb.y); c[rr][6] = f2bf(bb.z); c[rr][7] = f2bf(bb.w);
  }
  // K fragment order: d0 = dseg*16 + hi*8 exactly
  char* gkv = wsb + (size_t)bid * TILE_B;
  const int dseg = d0 >> 4;
  const int hi = (d0 >> 3) & 1;
#pragma unroll
  for (int rr = 0; rr < 4; ++rr) {
    const int k = kr + rr;
    u16x8 o = {c[rr][0], c[rr][1], c[rr][2], c[rr][3],
               c[rr][4], c[rr][5], c[rr][6], c[rr][7]};
    const int off = ((((k >> 5) * 8 + dseg) * 64) + hi * 32 + (k & 31)) << 4;
    *(u16x8*)(gkv + off) = o;
  }
  // V fragment order: k rows kr..kr+3 share (ks,kc,hi2), j0 = kr&7
  char* gkt = wsb + KV_REGION + (size_t)bid * TILE_B;
  const int ks = kr >> 5;
  const int kc = (kr >> 4) & 1;
  const int hi2 = (kr >> 3) & 1;
  const int j0 = kr & 7;                 // 0 or 4
#pragma unroll
  for (int cc = 0; cc < 8; ++cc) {
    const int d = d0 + cc;
    u16x4 o = {c[0][cc], c[1][cc], c[2][cc], c[3][cc]};
    const int off = (((((ks * 2 + kc) * 4 + (d >> 5)) * 64) + hi2 * 32 + (d & 31)) << 4) + j0 * 2;
    *(u16x4*)(gkt + off) = o;
  }
}

// ---------------- main attention kernel: pair (a, 31-a), 33 steps/block -----
__global__ void __launch_bounds__(256)
evo_attn3(const char* __restrict__ wsb, float* __restrict__ out) {
  // kb0 | kb1 | vb0 | vb1 = 64 KB (K and V tiles double-buffered)
  __shared__ char smem[4 * TILE_B];

  const int t = threadIdx.x;
  const int lane = t & 63;
  const int w = t >> 6;        // wave 0..3
  const int hi = lane >> 5;    // 0/1
  const int q31 = lane & 31;   // q (or k, or d) index within 32
  const int qhalf = w >> 1;    // rows [32*qhalf, +32)
  const int ks = w & 1;        // k-half [32*ks, +32) of each 64-k tile

  const int blk = blockIdx.x;            // 512 blocks
  const int bh = (blk & 7) * 4 + (blk >> 7);   // XCD-affine
  const int a = (blk >> 3) & 15;         // pair: q-tiles a and 31-a
  const int b = bh >> 4;
  const int h = bh & 15;

  const char* gkv = wsb + (size_t)bh * (NTILES * TILE_B);
  const char* gkt = wsb + KV_REGION + (size_t)bh * (NTILES * TILE_B);
  const int l16 = lane * 16;

  // stage one 16KB tile: wave w takes chunks 4w..4w+3 (dest wave-uniform +lane*16)
#define STG(BASEOFF, REGION, KT)                                           \
  {                                                                        \
    char* dst_ = smem + (BASEOFF) + w * 4096;                              \
    const char* src_ = (REGION) + (size_t)(KT) * TILE_B + w * 4096 + l16;  \
    _Pragma("unroll")                                                      \
    for (int i_ = 0; i_ < 4; ++i_) gl_lds16(src_ + i_ * 1024, dst_ + i_ * 1024); \
  }

#pragma unroll 1
  for (int seg = 0; seg < 2; ++seg) {
    const int qt = seg ? (31 - a) : a;   // q-tile (64 rows at 64*qt)
    const int nt = qt + 1;               // s=0 -> diag tile qt; s>0 -> tile s-1

    STG(0, gkv, qt);                     // K(diag) -> kb0
    STG(2 * TILE_B, gkt, qt);            // V(diag) -> vb0

    bf16x8 qf[8];
    f32x16 acc[4];
#pragma unroll
    for (int dt = 0; dt < 4; ++dt)
#pragma unroll
      for (int r = 0; r < 16; ++r) acc[dt][r] = 0.f;
    float mrun = -1e30f;   // raw score domain
    float lrun = 0.f;

    for (int s = 0; s < nt; ++s) {
      asm volatile("s_waitcnt vmcnt(0)" ::: "memory");
      __builtin_amdgcn_s_barrier();
      asm volatile("" ::: "memory");

      if (s == 0) {  // Q frags from kb0 (diag tile IS the Q tile)
#pragma unroll
        for (int d = 0; d < 8; ++d)
          qf[d] = *(const bf16x8*)(smem + (qhalf * 8 + d) * 1024 + l16);
      }
      if (s + 1 < nt) {  // prefetch tile(s+1)=s into the other buffers
        STG(((s + 1) & 1) * TILE_B, gkv, s);
        STG(2 * TILE_B + ((s + 1) & 1) * TILE_B, gkt, s);
      }
      const char* kb = smem + (s & 1) * TILE_B;
      const char* vbb = smem + 2 * TILE_B + (s & 1) * TILE_B;
      const bool inactive = (s == 0) && (qhalf == 0) && (ks == 1);

      if (!inactive) {
        // S^T(32k x 32q) = K * Q^T over d=128: 8 chained mfma32.
        // lane (hi,q31) reg r: S[k = ks*32 + (r&3)+8*(r>>2)+4*hi][q = q31]
        f32x16 st;
#pragma unroll
        for (int r = 0; r < 16; ++r) st[r] = 0.f;
        __builtin_amdgcn_s_setprio(1);
#pragma unroll
        for (int d = 0; d < 8; ++d) {
          bf16x8 kf = *(const bf16x8*)(kb + (ks * 8 + d) * 1024 + l16);
          st = mfma32(kf, qf[d], st);
        }
        __builtin_amdgcn_s_setprio(0);

        float sv[16];
#pragma unroll
        for (int r = 0; r < 16; ++r) sv[r] = st[r];

        if (s == 0) {  // diagonal causal mask
#pragma unroll
          for (int r = 0; r < 16; ++r) {
            const int krow = ks * 32 + (r & 3) + 8 * (r >> 2) + 4 * hi;
            if (krow > qhalf * 32 + q31) sv[r] = -1e30f;
          }
        }

        // row max: 16 in-lane + partner hi lane
        float m0 = fmaxf(fmaxf(sv[0], sv[1]), fmaxf(sv[2], sv[3]));
        float m1 = fmaxf(fmaxf(sv[4], sv[5]), fmaxf(sv[6], sv[7]));
        float m2 = fmaxf(fmaxf(sv[8], sv[9]), fmaxf(sv[10], sv[11]));
        float m3 = fmaxf(fmaxf(sv[12], sv[13]), fmaxf(sv[14], sv[15]));
        float tmax = fmaxf(fmaxf(m0, m1), fmaxf(m2, m3));
        tmax = fmaxf(tmax, __shfl_xor(tmax, 32));

        float pf[16];
        if (__all(tmax <= mrun)) {
          const float nmc = -mrun * SCALE_LOG2E;
#pragma unroll
          for (int r = 0; r < 16; ++r) pf[r] = exp2f(fmaf(sv[r], SCALE_LOG2E, nmc));
        } else {
          const float mnew = fmaxf(mrun, tmax);
          const float al = exp2f((mrun - mnew) * SCALE_LOG2E);
          mrun = mnew;
          const float nmc = -mnew * SCALE_LOG2E;
#pragma unroll
          for (int r = 0; r < 16; ++r) pf[r] = exp2f(fmaf(sv[r], SCALE_LOG2E, nmc));
          lrun *= al;
          float ar[16];
#pragma unroll
          for (int r = 0; r < 16; ++r)
            ar[r] = __shfl(al, (r & 3) + 8 * (r >> 2) + 4 * hi);
#pragma unroll
          for (int dt = 0; dt < 4; ++dt)
#pragma unroll
            for (int r = 0; r < 16; ++r) acc[dt][r] *= ar[r];
        }
        {
          float s01 = (pf[0] + pf[1]) + (pf[2] + pf[3]);
          float s23 = (pf[4] + pf[5]) + (pf[6] + pf[7]);
          float s45 = (pf[8] + pf[9]) + (pf[10] + pf[11]);
          float s67 = (pf[12] + pf[13]) + (pf[14] + pf[15]);
          lrun += (s01 + s23) + (s45 + s67);
        }

        // P -> registers: PV A-frag lane (hi,q31) needs P[q31][kc*16+hi*8+j].
        // per kc: {w0,w2}=permlane32_swap(cvtpk(p0,p1),cvtpk(p4,p5));
        //          {w1,w3}=permlane32_swap(cvtpk(p2,p3),cvtpk(p6,p7))
        bf16x8 pa0, pa1;
        {
          unsigned A = cvtpk(pf[0], pf[1]), B = cvtpk(pf[2], pf[3]);
          unsigned C = cvtpk(pf[4], pf[5]), D = cvtpk(pf[6], pf[7]);
          u32x2 s0 = __builtin_amdgcn_permlane32_swap(A, C, false, false);
          u32x2 s1 = __builtin_amdgcn_permlane32_swap(B, D, false, false);
          u32x4 pw = {s0.x, s1.x, s0.y, s1.y};
          pa0 = __builtin_bit_cast(bf16x8, pw);
        }
        {
          unsigned A = cvtpk(pf[8], pf[9]), B = cvtpk(pf[10], pf[11]);
          unsigned C = cvtpk(pf[12], pf[13]), D = cvtpk(pf[14], pf[15]);
          u32x2 s0 = __builtin_amdgcn_permlane32_swap(A, C, false, false);
          u32x2 s1 = __builtin_amdgcn_permlane32_swap(B, D, false, false);
          u32x4 pw = {s0.x, s1.x, s0.y, s1.y};
          pa1 = __builtin_bit_cast(bf16x8, pw);
        }

        // PV: acc[dtile] += P(32q x 32k) * V(32k x 32d); V frags linear
        __builtin_amdgcn_s_setprio(1);
#pragma unroll
        for (int dt = 0; dt < 4; ++dt) {
          bf16x8 vb = *(const bf16x8*)(vbb + ((ks * 2 + 0) * 4 + dt) * 1024 + l16);
          acc[dt] = mfma32(pa0, vb, acc[dt]);
        }
#pragma unroll
        for (int dt = 0; dt < 4; ++dt) {
          bf16x8 vb = *(const bf16x8*)(vbb + ((ks * 2 + 1) * 4 + dt) * 1024 + l16);
          acc[dt] = mfma32(pa1, vb, acc[dt]);
        }
        __builtin_amdgcn_s_setprio(0);
      }
    }

    // ---- merge the k-split pair (w and w^1) and write out ----
    lrun += __shfl_xor(lrun, 32);        // full row sum within this wave
    __builtin_amdgcn_s_barrier();        // all compute done; LDS reusable
    asm volatile("" ::: "memory");

    float* mex = (float*)smem;           // [w][q31] m, then l at +128
    if (hi == 0) {
      mex[w * 32 + q31] = mrun;
      mex[128 + w * 32 + q31] = lrun;
    }
    asm volatile("s_waitcnt lgkmcnt(0)" ::: "memory");
    __builtin_amdgcn_s_barrier();
    asm volatile("" ::: "memory");

    const int pw_ = w ^ 1;
    const float mp = mex[pw_ * 32 + q31];
    const float lp = mex[128 + pw_ * 32 + q31];
    const float M = fmaxf(mrun, mp);
    const float as_ = exp2f((mrun - M) * SCALE_LOG2E);
    const float ap_ = exp2f((mp - M) * SCALE_LOG2E);
    const float L = as_ * lrun + ap_ * lp;
    const float sc = as_ / L;            // this wave's scale, per q31 row

    float scr[16];
#pragma unroll
    for (int r = 0; r < 16; ++r)
      scr[r] = __shfl(sc, (r & 3) + 8 * (r >> 2) + 4 * hi);
#pragma unroll
    for (int dt = 0; dt < 4; ++dt)
#pragma unroll
      for (int r = 0; r < 16; ++r) acc[dt][r] *= scr[r];

    char* xch = smem + 1024 + qhalf * 17408 + lane * 272;
    if (ks == 1) {   // ks=1 wave deposits its scaled partial
#pragma unroll
      for (int dt = 0; dt < 4; ++dt)
#pragma unroll
        for (int rq = 0; rq < 4; ++rq) {
          f32x4 sl = {acc[dt][rq * 4], acc[dt][rq * 4 + 1],
                      acc[dt][rq * 4 + 2], acc[dt][rq * 4 + 3]};
          *(f32x4*)(xch + (dt * 4 + rq) * 16) = sl;
        }
    }
    asm volatile("s_waitcnt lgkmcnt(0)" ::: "memory");
    __builtin_amdgcn_s_barrier();
    asm volatile("" ::: "memory");

    if (ks == 0) {   // ks=0 wave combines and writes the final output
      float* ob = out + ((size_t)b * TL + qt * 64 + qhalf * 32) * TE + h * TD;
#pragma unroll
      for (int dt = 0; dt < 4; ++dt)
#pragma unroll
        for (int rq = 0; rq < 4; ++rq) {
          f32x4 p = *(const f32x4*)(xch + (dt * 4 + rq) * 16);
#pragma unroll
          for (int rr = 0; rr < 4; ++rr) {
            const int row = rr + 8 * rq + 4 * hi;
            ob[row * TE + dt * 32 + q31] = acc[dt][rq * 4 + rr] + p[rr];
          }
        }
    }
    __builtin_amdgcn_s_barrier();        // before next segment's staging
    asm volatile("" ::: "memory");
  }
}

// ---------------- fallback (v1-style, self-contained, no ws needed) ---------
__device__ __forceinline__ bf16x8 ld256s(const unsigned short* base, int row, int inrow) {
  const int off = (row * 256 + inrow) ^ ((row & 7) << 4);
  return *(const bf16x8*)((const char*)base + off);
}
__device__ __forceinline__ bf16x8 ld128s(const unsigned short* base, int row, int inrow) {
  const int off = (row * 128 + inrow) ^ ((row & 7) << 4);
  return *(const bf16x8*)((const char*)base + off);
}

__device__ __forceinline__ void stage_tile_fb(const float* __restrict__ src,
                                              unsigned short* kv, unsigned short* kvt,
                                              int t) {
  const int kr = (t >> 4) << 2;
  const int d0 = (t & 15) << 3;
  unsigned short c[4][8];
#pragma unroll
  for (int rr = 0; rr < 4; ++rr) {
    const float* p = src + (kr + rr) * TE + d0;
    const float4 a = *(const float4*)p;
    const float4 b = *(const float4*)(p + 4);
    c[rr][0] = f2bf(a.x); c[rr][1] = f2bf(a.y); c[rr][2] = f2bf(a.z); c[rr][3] = f2bf(a.w);
    c[rr][4] = f2bf(b.x); c[rr][5] = f2bf(b.y); c[rr][6] = f2bf(b.z); c[rr][7] = f2bf(b.w);
  }
#pragma unroll
  for (int rr = 0; rr < 4; ++rr) {
    const int r = kr + rr;
    u16x8 o = {c[rr][0], c[rr][1], c[rr][2], c[rr][3],
               c[rr][4], c[rr][5], c[rr][6], c[rr][7]};
    const int off = (r * 256 + d0 * 2) ^ ((r & 7) << 4);
    *(u16x8*)((char*)kv + off) = o;
  }
#pragma unroll
  for (int cc = 0; cc < 8; ++cc) {
    const int d = d0 + cc;
    u16x4 o = {c[0][cc], c[1][cc], c[2][cc], c[3][cc]};
    const int off = (d * 128 + kr * 2) ^ ((d & 7) << 4);
    *(u16x4*)((char*)kvt + off) = o;
  }
}

__global__ void __launch_bounds__(256)
evo_attn(const float* __restrict__ x, float* __restrict__ out) {
  __shared__ unsigned short kv[KB * TD];
  __shared__ unsigned short kvt[TD * KB];
  __shared__ unsigned short pl[4 * 16 * KB];

  const int t = threadIdx.x;
  const int lane = t & 63;
  const int w = t >> 6;
  const int g = lane >> 4;
  const int q15 = lane & 15;

  const int bh = blockIdx.x & 31;
  const int qt = 31 - (blockIdx.x >> 5);
  const int b = bh >> 4;
  const int h = bh & 15;
  const float* xb = x + (size_t)b * TL * TE + h * TD;
  const int q0 = qt * KB;

  stage_tile_fb(xb + (size_t)q0 * TE, kv, kvt, t);
  __syncthreads();

  bf16x8 qf[4];
#pragma unroll
  for (int c = 0; c < 4; ++c)
    qf[c] = ld256s(kv, 16 * w + q15, c * 64 + g * 16);

  f32x4 acc[8];
#pragma unroll
  for (int dt = 0; dt < 8; ++dt) acc[dt] = (f32x4){0.f, 0.f, 0.f, 0.f};
  float mrun = -1e30f;
  float lrun = 0.f;
  unsigned short* plw = pl + w * (16 * KB);

  for (int s = 0; s <= qt; ++s) {
    if (s > 0) {
      __syncthreads();
      stage_tile_fb(xb + (size_t)(s - 1) * KB * TE, kv, kvt, t);
      __syncthreads();
    }
    float sv[16];
#pragma unroll
    for (int kt2 = 0; kt2 < 4; ++kt2) {
      f32x4 st = (f32x4){0.f, 0.f, 0.f, 0.f};
#pragma unroll
      for (int c = 0; c < 4; ++c) {
        bf16x8 kf = ld256s(kv, kt2 * 16 + q15, c * 64 + g * 16);
        st = mfma16(kf, qf[c], st);
      }
#pragma unroll
      for (int r = 0; r < 4; ++r) sv[kt2 * 4 + r] = st[r] * SCALE_LOG2E;
    }
    if (s == 0) {
      const int qrel = 16 * w + q15;
#pragma unroll
      for (int kt2 = 0; kt2 < 4; ++kt2)
#pragma unroll
        for (int r = 0; r < 4; ++r)
          if (kt2 * 16 + g * 4 + r > qrel) sv[kt2 * 4 + r] = -1e30f;
    }
    float tmax = sv[0];
#pragma unroll
    for (int i = 1; i < 16; ++i) tmax = fmaxf(tmax, sv[i]);
    tmax = fmaxf(tmax, __shfl_xor(tmax, 16));
    tmax = fmaxf(tmax, __shfl_xor(tmax, 32));
    const float mnew = fmaxf(mrun, tmax);
    const float al = exp2f(mrun - mnew);
    mrun = mnew;
    float psum = 0.f;
    unsigned short pb[16];
#pragma unroll
    for (int i = 0; i < 16; ++i) {
      const float p = exp2f(sv[i] - mnew);
      psum += p;
      pb[i] = f2bf(p);
    }
    lrun = lrun * al + psum;
#pragma unroll
    for (int kt2 = 0; kt2 < 4; ++kt2) {
      u16x4 o = {pb[kt2 * 4], pb[kt2 * 4 + 1], pb[kt2 * 4 + 2], pb[kt2 * 4 + 3]};
      const int off = (q15 * 128 + kt2 * 32 + g * 8) ^ ((q15 & 7) << 4);
      *(u16x4*)((char*)plw + off) = o;
    }
    asm volatile("s_waitcnt lgkmcnt(0)" ::: "memory");
    float ar[4];
#pragma unroll
    for (int r = 0; r < 4; ++r) ar[r] = __shfl(al, g * 4 + r);
#pragma unroll
    for (int dt = 0; dt < 8; ++dt)
#pragma unroll
      for (int r = 0; r < 4; ++r) acc[dt][r] *= ar[r];
    bf16x8 pa0 = ld128s(plw, q15, g * 16);
    bf16x8 pa1 = ld128s(plw, q15, 64 + g * 16);
#pragma unroll
    for (int dt = 0; dt < 8; ++dt) {
      bf16x8 vb0 = ld128s(kvt, dt * 16 + q15, g * 16);
      bf16x8 vb1 = ld128s(kvt, dt * 16 + q15, 64 + g * 16);
      acc[dt] = mfma16(pa0, vb0, acc[dt]);
      acc[dt] = mfma16(pa1, vb1, acc[dt]);
    }
  }

  lrun += __shfl_xor(lrun, 16);
  lrun += __shfl_xor(lrun, 32);
  const float inv = 1.f / lrun;
  float ir[4];
#pragma unroll
  for (int r = 0; r < 4; ++r) ir[r] = __shfl(inv, g * 4 + r);
  float* ob = out + ((size_t)b * TL + q0 + 16 * w) * TE + h * TD;
#pragma unroll
  for (int dt = 0; dt < 8; ++dt)
#pragma unroll
    for (int r = 0; r < 4; ++r)
      ob[(g * 4 + r) * TE + dt * 16 + q15] = acc[dt][r] * ir[r];
}

extern "C" void kernel_launch(void* const* d_in, const int* in_sizes, int n_in,
                              void* d_out, int out_size, void* d_ws, size_t ws_size,
                              hipStream_t stream) {
  const float* x = (const float*)d_in[0];
  float* out = (float*)d_out;
  (void)in_sizes; (void)n_in; (void)out_size;
  if (ws_size >= (size_t)WS_NEED) {
    char* wsb = (char*)d_ws;
    prepack<<<dim3(1024), dim3(256), 0, stream>>>(x, wsb);
    evo_attn3<<<dim3(512), dim3(256), 0, stream>>>(wsb, out);
  } else {
    evo_attn<<<dim3(1024), dim3(256), 0, stream>>>(x, out);
  }
}

// Round 11
// 142.307 us; speedup vs baseline: 1.0261x; 1.0261x over previous
//
#include <hip/hip_runtime.h>
#include <hip/hip_bf16.h>

// EvoAttn: causal self-attention with Q=K=V = x.reshape(B,L,H,D).
// B=2 H=16 L=2048 D=128, fp32 in/out, bf16 MFMA compute.
// v11 = v9 (balanced pairs + fragment-order K) with V global->register
//       (deep prefetch: VLOAD(s+1) issued a full step ahead), 40KB LDS,
//       2 barriers + 1 vmcnt per step.

#define TL 2048
#define TE 2048
#define TD 128
#define KB 64
#define NTILES 32                          // TL / KB
#define TILE_B 16384                       // 64*128*2 bytes
#define KV_REGION (32 * NTILES * TILE_B)   // 16 MB per layout
#define WS_NEED (2u * (unsigned)KV_REGION) // 32 MB

typedef __attribute__((ext_vector_type(8))) short bf16x8;
typedef __attribute__((ext_vector_type(4))) float f32x4;
typedef __attribute__((ext_vector_type(8))) unsigned short u16x8;
typedef __attribute__((ext_vector_type(4))) unsigned short u16x4;

// (1/sqrt(128)) * log2(e)
#define SCALE_LOG2E 0.12751879f

__device__ __forceinline__ unsigned short f2bf(float f) {
  __hip_bfloat16 h = __float2bfloat16(f);
  return __builtin_bit_cast(unsigned short, h);
}

__device__ __forceinline__ f32x4 mfma16(bf16x8 a, bf16x8 b, f32x4 c) {
  return __builtin_amdgcn_mfma_f32_16x16x32_bf16(a, b, c, 0, 0, 0);
}

__device__ __forceinline__ void gl_lds16(const void* g, void* l) {
  __builtin_amdgcn_global_load_lds(
      (__attribute__((address_space(1))) void*)(g),
      (__attribute__((address_space(3))) void*)(l), 16, 0, 0);
}

// ws layout (per tile bid = bh*32 + kt):
// K region: 16B frag (kt2,c,g,q15) at ((kt2*4+c)*64 + g*16 + q15)*16
//   holding K[kt2*16+q15][c*32+g*8 .. +8).
// V region: 16B frag (half,dt,g,q15) at ((half*8+dt)*64 + g*16 + q15)*16
//   holding V[k=half*32+g*8+j][d=dt*16+q15].
__global__ void __launch_bounds__(256)
prepack(const float* __restrict__ x, char* __restrict__ wsb) {
  const int bid = blockIdx.x;            // bh*32 + kt
  const int kt = bid & 31;
  const int bh = bid >> 5;
  const int b = bh >> 4;
  const int h = bh & 15;
  const float* src = x + (size_t)b * TL * TE + h * TD + (size_t)kt * KB * TE;
  const int t = threadIdx.x;
  const int kr = (t >> 4) << 2;          // 4 consecutive k-rows
  const int d0 = (t & 15) << 3;          // 8 d-cols
  unsigned short c[4][8];
#pragma unroll
  for (int rr = 0; rr < 4; ++rr) {
    const float* p = src + (kr + rr) * TE + d0;
    const float4 a = *(const float4*)p;
    const float4 bb = *(const float4*)(p + 4);
    c[rr][0] = f2bf(a.x);  c[rr][1] = f2bf(a.y);  c[rr][2] = f2bf(a.z);  c[rr][3] = f2bf(a.w);
    c[rr][4] = f2bf(bb.x); c[rr][5] = f2bf(bb.y); c[rr][6] = f2bf(bb.z); c[rr][7] = f2bf(bb.w);
  }
  // K fragment order
  char* gkv = wsb + (size_t)bid * TILE_B;
  const int kt2 = kr >> 4;
  const int q0r = kr & 15;
  const int cc_ = (t & 15) >> 2;
  const int gg_ = (t & 15) & 3;
#pragma unroll
  for (int rr = 0; rr < 4; ++rr) {
    u16x8 o = {c[rr][0], c[rr][1], c[rr][2], c[rr][3],
               c[rr][4], c[rr][5], c[rr][6], c[rr][7]};
    const int off = (((kt2 * 4 + cc_) * 64 + gg_ * 16 + (q0r + rr)) << 4);
    *(u16x8*)(gkv + off) = o;
  }
  // V fragment order
  char* gkt = wsb + KV_REGION + (size_t)bid * TILE_B;
  const int half = kr >> 5;
  const int g = (kr >> 3) & 3;
  const int j0 = kr & 7;                 // 0 or 4
#pragma unroll
  for (int cc = 0; cc < 8; ++cc) {
    const int d = d0 + cc;
    u16x4 o = {c[0][cc], c[1][cc], c[2][cc], c[3][cc]};   // k = kr..kr+3
    const int off = (((half * 8 + (d >> 4)) * 64 + g * 16 + (d & 15)) << 4) + j0 * 2;
    *(u16x4*)(gkt + off) = o;
  }
}

// ---------------- main attention kernel: pair (a, 31-a), 33 steps/block -----
__global__ void __launch_bounds__(256)
evo_attn4(const char* __restrict__ wsb, float* __restrict__ out) {
  // kv0 | kv1 | pl(4 waves x 2KB) = 40 KB
  __shared__ char smem[2 * TILE_B + 8192];

  const int t = threadIdx.x;
  const int lane = t & 63;
  const int w = t >> 6;        // wave 0..3, owns q rows [q0+16w, q0+16w+16)
  const int g = lane >> 4;
  const int q15 = lane & 15;

  const int blk = blockIdx.x;            // 512 blocks
  const int bh = (blk & 7) * 4 + (blk >> 7);   // XCD-affine
  const int a = (blk >> 3) & 15;         // pair: q-tiles a and 31-a
  const int b = bh >> 4;
  const int h = bh & 15;

  const char* gkv = wsb + (size_t)bh * (NTILES * TILE_B);
  const char* gkt = wsb + KV_REGION + (size_t)bh * (NTILES * TILE_B);
  char* plw = smem + 2 * TILE_B + w * 2048;
  const int l16 = lane * 16;

#define STAGE_KV(BUFI, KT)                                                 \
  {                                                                        \
    char* dst_ = smem + (BUFI) * TILE_B + (t >> 6) * 1024;                 \
    const char* src_ = gkv + (size_t)(KT) * TILE_B + t * 16;               \
    _Pragma("unroll")                                                      \
    for (int i_ = 0; i_ < 4; ++i_) gl_lds16(src_ + i_ * 4096, dst_ + i_ * 4096); \
  }

  // tile index for step s of segment qt: s=0 -> diag(qt), s>0 -> s-1
#define TIDX(S) (((S) == 0) ? qt : ((S)-1))

  bf16x8 vbr[2][8];
#define VLOAD(S)                                                           \
  {                                                                        \
    const char* vt_ = gkt + (size_t)TIDX(S) * TILE_B + l16;                \
    _Pragma("unroll")                                                      \
    for (int h_ = 0; h_ < 2; ++h_)                                         \
      _Pragma("unroll")                                                    \
      for (int d_ = 0; d_ < 8; ++d_)                                       \
        vbr[h_][d_] = *(const bf16x8*)(vt_ + (h_ * 8 + d_) * 1024);        \
  }

#pragma unroll 1
  for (int seg = 0; seg < 2; ++seg) {
    const int qt = seg ? (31 - a) : a;   // q-tile (64 rows at 64*qt)
    const int nt = qt + 1;

    // prologue: kv(0)=diag -> buf0, kv(1)=tile0 -> buf1, V(0)=diag -> regs
    STAGE_KV(0, qt);
    if (nt > 1) STAGE_KV(1, 0);
    VLOAD(0);
    if (nt > 1) asm volatile("s_waitcnt vmcnt(20)" ::: "memory");
    else        asm volatile("s_waitcnt vmcnt(16)" ::: "memory");
    __builtin_amdgcn_s_barrier();
    asm volatile("" ::: "memory");

    // Q fragments from buf0 (diag tile IS the Q tile); kt2 = w
    bf16x8 qf[4];
#pragma unroll
    for (int c = 0; c < 4; ++c)
      qf[c] = *(const bf16x8*)(smem + (w * 4 + c) * 1024 + l16);

    f32x4 acc[8];
#pragma unroll
    for (int dt = 0; dt < 8; ++dt) acc[dt] = (f32x4){0.f, 0.f, 0.f, 0.f};
    float mrun = -1e30f;   // raw score domain
    float lrun = 0.f;

    for (int s = 0; s < nt; ++s) {
      if (s > 0) {
        // kv(s) already drained by previous iteration's vmcnt; just sync.
        __builtin_amdgcn_s_barrier();
        asm volatile("" ::: "memory");
      }
      const char* kv = smem + (s & 1) * TILE_B;

      // QK^T: lane (g,q15) holds S[k=kt2*16+g*4+r][q=16w+q15] (raw)
      float sv[16];
      __builtin_amdgcn_s_setprio(1);
#pragma unroll
      for (int kt2 = 0; kt2 < 4; ++kt2) {
        f32x4 st = (f32x4){0.f, 0.f, 0.f, 0.f};
#pragma unroll
        for (int c = 0; c < 4; ++c) {
          bf16x8 kf = *(const bf16x8*)(kv + (kt2 * 4 + c) * 1024 + l16);
          st = mfma16(kf, qf[c], st);
        }
#pragma unroll
        for (int r = 0; r < 4; ++r) sv[kt2 * 4 + r] = st[r];
      }
      __builtin_amdgcn_s_setprio(0);

      __builtin_amdgcn_s_barrier();      // all waves done reading kv(s)
      asm volatile("" ::: "memory");
      if (s + 2 < nt) STAGE_KV(s & 1, s + 1);   // kv for step s+2

      if (s == 0) {  // diagonal causal mask
        const int qrel = 16 * w + q15;
#pragma unroll
        for (int kt2 = 0; kt2 < 4; ++kt2)
#pragma unroll
          for (int r = 0; r < 4; ++r)
            if (kt2 * 16 + g * 4 + r > qrel) sv[kt2 * 4 + r] = -1e30f;
      }

      // online softmax, defer-max fast path
      float m0 = fmaxf(fmaxf(sv[0], sv[1]), fmaxf(sv[2], sv[3]));
      float m1 = fmaxf(fmaxf(sv[4], sv[5]), fmaxf(sv[6], sv[7]));
      float m2 = fmaxf(fmaxf(sv[8], sv[9]), fmaxf(sv[10], sv[11]));
      float m3 = fmaxf(fmaxf(sv[12], sv[13]), fmaxf(sv[14], sv[15]));
      float tmax = fmaxf(fmaxf(m0, m1), fmaxf(m2, m3));
      tmax = fmaxf(tmax, __shfl_xor(tmax, 16));
      tmax = fmaxf(tmax, __shfl_xor(tmax, 32));

      float pf[16];
      if (__all(tmax <= mrun)) {
        const float nmc = -mrun * SCALE_LOG2E;
#pragma unroll
        for (int i = 0; i < 16; ++i) pf[i] = exp2f(fmaf(sv[i], SCALE_LOG2E, nmc));
      } else {
        const float mnew = fmaxf(mrun, tmax);
        const float al = exp2f((mrun - mnew) * SCALE_LOG2E);
        mrun = mnew;
        const float nmc = -mnew * SCALE_LOG2E;
#pragma unroll
        for (int i = 0; i < 16; ++i) pf[i] = exp2f(fmaf(sv[i], SCALE_LOG2E, nmc));
        lrun *= al;
        float ar[4];
#pragma unroll
        for (int r = 0; r < 4; ++r) ar[r] = __shfl(al, g * 4 + r);
#pragma unroll
        for (int dt = 0; dt < 8; ++dt)
#pragma unroll
          for (int r = 0; r < 4; ++r) acc[dt][r] *= ar[r];
      }
      {
        float s01 = (pf[0] + pf[1]) + (pf[2] + pf[3]);
        float s23 = (pf[4] + pf[5]) + (pf[6] + pf[7]);
        float s45 = (pf[8] + pf[9]) + (pf[10] + pf[11]);
        float s67 = (pf[12] + pf[13]) + (pf[14] + pf[15]);
        lrun += (s01 + s23) + (s45 + s67);
      }

      // P -> per-wave LDS as [k-octet m][q15] 16B units (conflict-free read)
      {
        const int wb = q15 * 16 + (g & 1) * 8;
#pragma unroll
        for (int kt2 = 0; kt2 < 4; ++kt2) {
          u16x4 o = {f2bf(pf[kt2 * 4]), f2bf(pf[kt2 * 4 + 1]),
                     f2bf(pf[kt2 * 4 + 2]), f2bf(pf[kt2 * 4 + 3])};
          *(u16x4*)(plw + (kt2 * 2 + (g >> 1)) * 256 + wb) = o;
        }
      }
      asm volatile("s_waitcnt lgkmcnt(0)" ::: "memory");

      // wait V(s) regs (issued a full step ago); leave only kv(s+2) stage
      if (s + 2 < nt) asm volatile("s_waitcnt vmcnt(4)" ::: "memory");
      else            asm volatile("s_waitcnt vmcnt(0)" ::: "memory");

      // PV: acc[dt] += P(16x64) * V(64x16 slice dt); V from registers
      bf16x8 pa0 = *(const bf16x8*)(plw + g * 256 + q15 * 16);
      bf16x8 pa1 = *(const bf16x8*)(plw + (4 + g) * 256 + q15 * 16);
      __builtin_amdgcn_s_setprio(1);
#pragma unroll
      for (int dt = 0; dt < 8; ++dt) {
        acc[dt] = mfma16(pa0, vbr[0][dt], acc[dt]);
        acc[dt] = mfma16(pa1, vbr[1][dt], acc[dt]);
      }
      __builtin_amdgcn_s_setprio(0);

      if (s + 1 < nt) VLOAD(s + 1);    // deep prefetch: consumed next step
    }

    // combine g-group partial sums, normalize, write out
    lrun += __shfl_xor(lrun, 16);
    lrun += __shfl_xor(lrun, 32);
    const float inv = 1.f / lrun;
    float ir[4];
#pragma unroll
    for (int r = 0; r < 4; ++r) ir[r] = __shfl(inv, g * 4 + r);

    float* ob = out + ((size_t)b * TL + qt * 64 + 16 * w) * TE + h * TD;
#pragma unroll
    for (int dt = 0; dt < 8; ++dt)
#pragma unroll
      for (int r = 0; r < 4; ++r)
        ob[(g * 4 + r) * TE + dt * 16 + q15] = acc[dt][r] * ir[r];

    __builtin_amdgcn_s_barrier();  // protect buffers before next segment
    asm volatile("" ::: "memory");
  }
}

// ---------------- fallback (v1-style, self-contained, no ws needed) ---------
__device__ __forceinline__ bf16x8 ld256s(const unsigned short* base, int row, int inrow) {
  const int off = (row * 256 + inrow) ^ ((row & 7) << 4);
  return *(const bf16x8*)((const char*)base + off);
}
__device__ __forceinline__ bf16x8 ld128s(const unsigned short* base, int row, int inrow) {
  const int off = (row * 128 + inrow) ^ ((row & 7) << 4);
  return *(const bf16x8*)((const char*)base + off);
}

__device__ __forceinline__ void stage_tile_fb(const float* __restrict__ src,
                                              unsigned short* kv, unsigned short* kvt,
                                              int t) {
  const int kr = (t >> 4) << 2;
  const int d0 = (t & 15) << 3;
  unsigned short c[4][8];
#pragma unroll
  for (int rr = 0; rr < 4; ++rr) {
    const float* p = src + (kr + rr) * TE + d0;
    const float4 a = *(const float4*)p;
    const float4 b = *(const float4*)(p + 4);
    c[rr][0] = f2bf(a.x); c[rr][1] = f2bf(a.y); c[rr][2] = f2bf(a.z); c[rr][3] = f2bf(a.w);
    c[rr][4] = f2bf(b.x); c[rr][5] = f2bf(b.y); c[rr][6] = f2bf(b.z); c[rr][7] = f2bf(b.w);
  }
#pragma unroll
  for (int rr = 0; rr < 4; ++rr) {
    const int r = kr + rr;
    u16x8 o = {c[rr][0], c[rr][1], c[rr][2], c[rr][3],
               c[rr][4], c[rr][5], c[rr][6], c[rr][7]};
    const int off = (r * 256 + d0 * 2) ^ ((r & 7) << 4);
    *(u16x8*)((char*)kv + off) = o;
  }
#pragma unroll
  for (int cc = 0; cc < 8; ++cc) {
    const int d = d0 + cc;
    u16x4 o = {c[0][cc], c[1][cc], c[2][cc], c[3][cc]};
    const int off = (d * 128 + kr * 2) ^ ((d & 7) << 4);
    *(u16x4*)((char*)kvt + off) = o;
  }
}

__global__ void __launch_bounds__(256)
evo_attn(const float* __restrict__ x, float* __restrict__ out) {
  __shared__ unsigned short kv[KB * TD];
  __shared__ unsigned short kvt[TD * KB];
  __shared__ unsigned short pl[4 * 16 * KB];

  const int t = threadIdx.x;
  const int lane = t & 63;
  const int w = t >> 6;
  const int g = lane >> 4;
  const int q15 = lane & 15;

  const int bh = blockIdx.x & 31;
  const int qt = 31 - (blockIdx.x >> 5);
  const int b = bh >> 4;
  const int h = bh & 15;
  const float* xb = x + (size_t)b * TL * TE + h * TD;
  const int q0 = qt * KB;

  stage_tile_fb(xb + (size_t)q0 * TE, kv, kvt, t);
  __syncthreads();

  bf16x8 qf[4];
#pragma unroll
  for (int c = 0; c < 4; ++c)
    qf[c] = ld256s(kv, 16 * w + q15, c * 64 + g * 16);

  f32x4 acc[8];
#pragma unroll
  for (int dt = 0; dt < 8; ++dt) acc[dt] = (f32x4){0.f, 0.f, 0.f, 0.f};
  float mrun = -1e30f;
  float lrun = 0.f;
  unsigned short* plw = pl + w * (16 * KB);

  for (int s = 0; s <= qt; ++s) {
    if (s > 0) {
      __syncthreads();
      stage_tile_fb(xb + (size_t)(s - 1) * KB * TE, kv, kvt, t);
      __syncthreads();
    }
    float sv[16];
#pragma unroll
    for (int kt2 = 0; kt2 < 4; ++kt2) {
      f32x4 st = (f32x4){0.f, 0.f, 0.f, 0.f};
#pragma unroll
      for (int c = 0; c < 4; ++c) {
        bf16x8 kf = ld256s(kv, kt2 * 16 + q15, c * 64 + g * 16);
        st = mfma16(kf, qf[c], st);
      }
#pragma unroll
      for (int r = 0; r < 4; ++r) sv[kt2 * 4 + r] = st[r] * SCALE_LOG2E;
    }
    if (s == 0) {
      const int qrel = 16 * w + q15;
#pragma unroll
      for (int kt2 = 0; kt2 < 4; ++kt2)
#pragma unroll
        for (int r = 0; r < 4; ++r)
          if (kt2 * 16 + g * 4 + r > qrel) sv[kt2 * 4 + r] = -1e30f;
    }
    float tmax = sv[0];
#pragma unroll
    for (int i = 1; i < 16; ++i) tmax = fmaxf(tmax, sv[i]);
    tmax = fmaxf(tmax, __shfl_xor(tmax, 16));
    tmax = fmaxf(tmax, __shfl_xor(tmax, 32));
    const float mnew = fmaxf(mrun, tmax);
    const float al = exp2f(mrun - mnew);
    mrun = mnew;
    float psum = 0.f;
    unsigned short pb[16];
#pragma unroll
    for (int i = 0; i < 16; ++i) {
      const float p = exp2f(sv[i] - mnew);
      psum += p;
      pb[i] = f2bf(p);
    }
    lrun = lrun * al + psum;
#pragma unroll
    for (int kt2 = 0; kt2 < 4; ++kt2) {
      u16x4 o = {pb[kt2 * 4], pb[kt2 * 4 + 1], pb[kt2 * 4 + 2], pb[kt2 * 4 + 3]};
      const int off = (q15 * 128 + kt2 * 32 + g * 8) ^ ((q15 & 7) << 4);
      *(u16x4*)((char*)plw + off) = o;
    }
    asm volatile("s_waitcnt lgkmcnt(0)" ::: "memory");
    float ar[4];
#pragma unroll
    for (int r = 0; r < 4; ++r) ar[r] = __shfl(al, g * 4 + r);
#pragma unroll
    for (int dt = 0; dt < 8; ++dt)
#pragma unroll
      for (int r = 0; r < 4; ++r) acc[dt][r] *= ar[r];
    bf16x8 pa0 = ld128s(plw, q15, g * 16);
    bf16x8 pa1 = ld128s(plw, q15, 64 + g * 16);
#pragma unroll
    for (int dt = 0; dt < 8; ++dt) {
      bf16x8 vb0 = ld128s(kvt, dt * 16 + q15, g * 16);
      bf16x8 vb1 = ld128s(kvt, dt * 16 + q15, 64 + g * 16);
      acc[dt] = mfma16(pa0, vb0, acc[dt]);
      acc[dt] = mfma16(pa1, vb1, acc[dt]);
    }
  }

  lrun += __shfl_xor(lrun, 16);
  lrun += __shfl_xor(lrun, 32);
  const float inv = 1.f / lrun;
  float ir[4];
#pragma unroll
  for (int r = 0; r < 4; ++r) ir[r] = __shfl(inv, g * 4 + r);
  float* ob = out + ((size_t)b * TL + q0 + 16 * w) * TE + h * TD;
#pragma unroll
  for (int dt = 0; dt < 8; ++dt)
#pragma unroll
    for (int r = 0; r < 4; ++r)
      ob[(g * 4 + r) * TE + dt * 16 + q15] = acc[dt][r] * ir[r];
}

extern "C" void kernel_launch(void* const* d_in, const int* in_sizes, int n_in,
                              void* d_out, int out_size, void* d_ws, size_t ws_size,
                              hipStream_t stream) {
  const float* x = (const float*)d_in[0];
  float* out = (float*)d_out;
  (void)in_sizes; (void)n_in; (void)out_size;
  if (ws_size >= (size_t)WS_NEED) {
    char* wsb = (char*)d_ws;
    prepack<<<dim3(1024), dim3(256), 0, stream>>>(x, wsb);
    evo_attn4<<<dim3(512), dim3(256), 0, stream>>>(wsb, out);
  } else {
    evo_attn<<<dim3(1024), dim3(256), 0, stream>>>(x, out);
  }
}

// Round 12
// 116.617 us; speedup vs baseline: 1.2521x; 1.2203x over previous
//
#include <hip/hip_runtime.h>
#include <hip/hip_bf16.h>

// EvoAttn: causal self-attention with Q=K=V = x.reshape(B,L,H,D).
// B=2 H=16 L=2048 D=128, fp32 in/out, bf16 MFMA compute.
// v12 = v9 skeleton with 32 q-rows per wave (2 q-subtiles): every K/V LDS
//       fragment read feeds 2 MFMAs (LDS-BW was the wall). 128-thr blocks
//       (2 waves), 512 blocks, balanced pair scheduling, fragment-order K/V.

#define TL 2048
#define TE 2048
#define TD 128
#define KB 64
#define NTILES 32                          // TL / KB
#define TILE_B 16384                       // 64*128*2 bytes
#define KV_REGION (32 * NTILES * TILE_B)   // 16 MB per layout
#define WS_NEED (2u * (unsigned)KV_REGION) // 32 MB

typedef __attribute__((ext_vector_type(8))) short bf16x8;
typedef __attribute__((ext_vector_type(4))) float f32x4;
typedef __attribute__((ext_vector_type(8))) unsigned short u16x8;
typedef __attribute__((ext_vector_type(4))) unsigned short u16x4;

// (1/sqrt(128)) * log2(e)
#define SCALE_LOG2E 0.12751879f

__device__ __forceinline__ unsigned short f2bf(float f) {
  __hip_bfloat16 h = __float2bfloat16(f);
  return __builtin_bit_cast(unsigned short, h);
}

__device__ __forceinline__ f32x4 mfma16(bf16x8 a, bf16x8 b, f32x4 c) {
  return __builtin_amdgcn_mfma_f32_16x16x32_bf16(a, b, c, 0, 0, 0);
}

__device__ __forceinline__ void gl_lds16(const void* g, void* l) {
  __builtin_amdgcn_global_load_lds(
      (__attribute__((address_space(1))) void*)(g),
      (__attribute__((address_space(3))) void*)(l), 16, 0, 0);
}

// ws layout (per tile bid = bh*32 + kt):
// K region: 16B frag (kt2,c,g,q15) at ((kt2*4+c)*64 + g*16 + q15)*16
//   holding K[kt2*16+q15][c*32+g*8 .. +8).
// V region: 16B frag (half,dt,g,q15) at ((half*8+dt)*64 + g*16 + q15)*16
//   holding V[k=half*32+g*8+j][d=dt*16+q15].
__global__ void __launch_bounds__(256)
prepack(const float* __restrict__ x, char* __restrict__ wsb) {
  const int bid = blockIdx.x;            // bh*32 + kt
  const int kt = bid & 31;
  const int bh = bid >> 5;
  const int b = bh >> 4;
  const int h = bh & 15;
  const float* src = x + (size_t)b * TL * TE + h * TD + (size_t)kt * KB * TE;
  const int t = threadIdx.x;
  const int kr = (t >> 4) << 2;          // 4 consecutive k-rows
  const int d0 = (t & 15) << 3;          // 8 d-cols
  unsigned short c[4][8];
#pragma unroll
  for (int rr = 0; rr < 4; ++rr) {
    const float* p = src + (kr + rr) * TE + d0;
    const float4 a = *(const float4*)p;
    const float4 bb = *(const float4*)(p + 4);
    c[rr][0] = f2bf(a.x);  c[rr][1] = f2bf(a.y);  c[rr][2] = f2bf(a.z);  c[rr][3] = f2bf(a.w);
    c[rr][4] = f2bf(bb.x); c[rr][5] = f2bf(bb.y); c[rr][6] = f2bf(bb.z); c[rr][7] = f2bf(bb.w);
  }
  // K fragment order
  char* gkv = wsb + (size_t)bid * TILE_B;
  const int kt2 = kr >> 4;
  const int q0r = kr & 15;
  const int cc_ = (t & 15) >> 2;
  const int gg_ = (t & 15) & 3;
#pragma unroll
  for (int rr = 0; rr < 4; ++rr) {
    u16x8 o = {c[rr][0], c[rr][1], c[rr][2], c[rr][3],
               c[rr][4], c[rr][5], c[rr][6], c[rr][7]};
    const int off = (((kt2 * 4 + cc_) * 64 + gg_ * 16 + (q0r + rr)) << 4);
    *(u16x8*)(gkv + off) = o;
  }
  // V fragment order
  char* gkt = wsb + KV_REGION + (size_t)bid * TILE_B;
  const int half = kr >> 5;
  const int g = (kr >> 3) & 3;
  const int j0 = kr & 7;                 // 0 or 4
#pragma unroll
  for (int cc = 0; cc < 8; ++cc) {
    const int d = d0 + cc;
    u16x4 o = {c[0][cc], c[1][cc], c[2][cc], c[3][cc]};   // k = kr..kr+3
    const int off = (((half * 8 + (d >> 4)) * 64 + g * 16 + (d & 15)) << 4) + j0 * 2;
    *(u16x4*)(gkt + off) = o;
  }
}

// ------- main kernel: 2 waves x 32 q-rows; pair (a, 31-a), 33 steps/block ---
__global__ void __launch_bounds__(128)
evo_attn5(const char* __restrict__ wsb, float* __restrict__ out) {
  // kv0 | kv1 | kvt | pl(2 waves x 4KB) = 56 KB -> 2 blocks/CU
  __shared__ char smem[3 * TILE_B + 8192];

  const int t = threadIdx.x;
  const int lane = t & 63;
  const int w = t >> 6;        // wave 0..1, owns q rows [32w, 32w+32)
  const int g = lane >> 4;
  const int q15 = lane & 15;

  const int blk = blockIdx.x;            // 512 blocks
  const int bh = (blk & 7) * 4 + (blk >> 7);   // XCD-affine
  const int a = (blk >> 3) & 15;         // pair: q-tiles a and 31-a
  const int b = bh >> 4;
  const int h = bh & 15;

  const char* gkv = wsb + (size_t)bh * (NTILES * TILE_B);
  const char* gkt = wsb + KV_REGION + (size_t)bh * (NTILES * TILE_B);
  char* plw = smem + 3 * TILE_B + w * 4096;
  const char* kvtb = smem + 2 * TILE_B;
  const int l16 = lane * 16;

  // stage one 16KB tile with 128 threads: 8 gl_lds16/thread.
  // LDS dest = wave-uniform base + lane*16 -> per-wave 8KB region.
#define STAGE_KV(BUFI, KT)                                                 \
  {                                                                        \
    char* dst_ = smem + (BUFI) * TILE_B + (t >> 6) * 8192;                 \
    const char* src_ = gkv + (size_t)(KT) * TILE_B + (t >> 6) * 8192 + l16;\
    _Pragma("unroll")                                                      \
    for (int i_ = 0; i_ < 8; ++i_) gl_lds16(src_ + i_ * 1024, dst_ + i_ * 1024); \
  }
#define STAGE_KVT(KT)                                                      \
  {                                                                        \
    char* dst_ = smem + 2 * TILE_B + (t >> 6) * 8192;                      \
    const char* src_ = gkt + (size_t)(KT) * TILE_B + (t >> 6) * 8192 + l16;\
    _Pragma("unroll")                                                      \
    for (int i_ = 0; i_ < 8; ++i_) gl_lds16(src_ + i_ * 1024, dst_ + i_ * 1024); \
  }

#pragma unroll 1
  for (int seg = 0; seg < 2; ++seg) {
    const int qt = seg ? (31 - a) : a;   // q-tile (64 rows at 64*qt)
    const int nt = qt + 1;               // s=0 diag(qt); s>0 -> tile s-1

    // prologue: diag kv -> buf0, kv tile0 -> buf1, diag kvt
    STAGE_KV(0, qt);
    if (nt > 1) STAGE_KV(1, 0);
    STAGE_KVT(qt);
    asm volatile("s_waitcnt vmcnt(0)" ::: "memory");
    __builtin_amdgcn_s_barrier();
    asm volatile("" ::: "memory");

    // Q fragments from buf0 (diag tile IS the Q tile): qsub qs -> kt2=2w+qs
    bf16x8 qf[2][4];
#pragma unroll
    for (int qs = 0; qs < 2; ++qs)
#pragma unroll
      for (int c = 0; c < 4; ++c)
        qf[qs][c] = *(const bf16x8*)(smem + ((2 * w + qs) * 4 + c) * 1024 + l16);

    f32x4 acc[2][8];
#pragma unroll
    for (int qs = 0; qs < 2; ++qs)
#pragma unroll
      for (int dt = 0; dt < 8; ++dt) acc[qs][dt] = (f32x4){0.f, 0.f, 0.f, 0.f};
    float mrun[2] = {-1e30f, -1e30f};
    float lrun[2] = {0.f, 0.f};

    for (int s = 0; s < nt; ++s) {
      if (s > 0) {  // kv(s) ready: drain all but [kvt(s):8, kv(s+1):8]
        asm volatile("s_waitcnt vmcnt(16)" ::: "memory");
        __builtin_amdgcn_s_barrier();
        asm volatile("" ::: "memory");
      }
      const char* kv = smem + (s & 1) * TILE_B;

      // QK^T: lane (g,q15), per qs: S[k=kt2*16+g*4+r][q=32w+16qs+q15] (raw)
      float pf[2][16];
      __builtin_amdgcn_s_setprio(1);
#pragma unroll
      for (int kt2 = 0; kt2 < 4; ++kt2) {
        f32x4 st0 = (f32x4){0.f, 0.f, 0.f, 0.f};
        f32x4 st1 = (f32x4){0.f, 0.f, 0.f, 0.f};
#pragma unroll
        for (int c = 0; c < 4; ++c) {
          bf16x8 kf = *(const bf16x8*)(kv + (kt2 * 4 + c) * 1024 + l16);
          st0 = mfma16(kf, qf[0][c], st0);
          st1 = mfma16(kf, qf[1][c], st1);
        }
#pragma unroll
        for (int r = 0; r < 4; ++r) {
          pf[0][kt2 * 4 + r] = st0[r];
          pf[1][kt2 * 4 + r] = st1[r];
        }
      }
      __builtin_amdgcn_s_setprio(0);

      if (s == 0) {  // diagonal causal mask
#pragma unroll
        for (int qs = 0; qs < 2; ++qs) {
          const int qrel = 32 * w + 16 * qs + q15;
#pragma unroll
          for (int kt2 = 0; kt2 < 4; ++kt2)
#pragma unroll
            for (int r = 0; r < 4; ++r)
              if (kt2 * 16 + g * 4 + r > qrel) pf[qs][kt2 * 4 + r] = -1e30f;
        }
      }

      // online softmax (defer-max), per q-subtile
      float tmax[2];
#pragma unroll
      for (int qs = 0; qs < 2; ++qs) {
        float m0 = fmaxf(fmaxf(pf[qs][0], pf[qs][1]), fmaxf(pf[qs][2], pf[qs][3]));
        float m1 = fmaxf(fmaxf(pf[qs][4], pf[qs][5]), fmaxf(pf[qs][6], pf[qs][7]));
        float m2 = fmaxf(fmaxf(pf[qs][8], pf[qs][9]), fmaxf(pf[qs][10], pf[qs][11]));
        float m3 = fmaxf(fmaxf(pf[qs][12], pf[qs][13]), fmaxf(pf[qs][14], pf[qs][15]));
        float tm = fmaxf(fmaxf(m0, m1), fmaxf(m2, m3));
        tm = fmaxf(tm, __shfl_xor(tm, 16));
        tm = fmaxf(tm, __shfl_xor(tm, 32));
        tmax[qs] = tm;
      }

      if (__all((tmax[0] <= mrun[0]) && (tmax[1] <= mrun[1]))) {
#pragma unroll
        for (int qs = 0; qs < 2; ++qs) {
          const float nmc = -mrun[qs] * SCALE_LOG2E;
#pragma unroll
          for (int i = 0; i < 16; ++i)
            pf[qs][i] = exp2f(fmaf(pf[qs][i], SCALE_LOG2E, nmc));
        }
      } else {
#pragma unroll
        for (int qs = 0; qs < 2; ++qs) {
          const float mnew = fmaxf(mrun[qs], tmax[qs]);
          const float al = exp2f((mrun[qs] - mnew) * SCALE_LOG2E);
          mrun[qs] = mnew;
          const float nmc = -mnew * SCALE_LOG2E;
#pragma unroll
          for (int i = 0; i < 16; ++i)
            pf[qs][i] = exp2f(fmaf(pf[qs][i], SCALE_LOG2E, nmc));
          lrun[qs] *= al;
          float ar[4];
#pragma unroll
          for (int r = 0; r < 4; ++r) ar[r] = __shfl(al, g * 4 + r);
#pragma unroll
          for (int dt = 0; dt < 8; ++dt)
#pragma unroll
            for (int r = 0; r < 4; ++r) acc[qs][dt][r] *= ar[r];
        }
      }

#pragma unroll
      for (int qs = 0; qs < 2; ++qs) {
        float s01 = (pf[qs][0] + pf[qs][1]) + (pf[qs][2] + pf[qs][3]);
        float s23 = (pf[qs][4] + pf[qs][5]) + (pf[qs][6] + pf[qs][7]);
        float s45 = (pf[qs][8] + pf[qs][9]) + (pf[qs][10] + pf[qs][11]);
        float s67 = (pf[qs][12] + pf[qs][13]) + (pf[qs][14] + pf[qs][15]);
        lrun[qs] += (s01 + s23) + (s45 + s67);
      }

      // P -> per-wave LDS as [k-octet m][q15] 16B units, per q-subtile
      {
        const int wb = q15 * 16 + (g & 1) * 8;
#pragma unroll
        for (int qs = 0; qs < 2; ++qs)
#pragma unroll
          for (int kt2 = 0; kt2 < 4; ++kt2) {
            u16x4 o = {f2bf(pf[qs][kt2 * 4]), f2bf(pf[qs][kt2 * 4 + 1]),
                       f2bf(pf[qs][kt2 * 4 + 2]), f2bf(pf[qs][kt2 * 4 + 3])};
            *(u16x4*)(plw + qs * 2048 + (kt2 * 2 + (g >> 1)) * 256 + wb) = o;
          }
      }
      asm volatile("s_waitcnt lgkmcnt(0)" ::: "memory");

      if (s > 0) {  // kvt(s) ready; leave kv(s+1):8 outstanding if staged
        if (s + 1 < nt) asm volatile("s_waitcnt vmcnt(8)" ::: "memory");
        else            asm volatile("s_waitcnt vmcnt(0)" ::: "memory");
        __builtin_amdgcn_s_barrier();
        asm volatile("" ::: "memory");
      }

      // PV: acc[qs][dt] += P(16x64) * V(64x16 slice dt); V frags shared by qs
      bf16x8 pa[2][2];
#pragma unroll
      for (int qs = 0; qs < 2; ++qs) {
        pa[qs][0] = *(const bf16x8*)(plw + qs * 2048 + g * 256 + q15 * 16);
        pa[qs][1] = *(const bf16x8*)(plw + qs * 2048 + (4 + g) * 256 + q15 * 16);
      }
      __builtin_amdgcn_s_setprio(1);
#pragma unroll
      for (int dt = 0; dt < 8; ++dt) {
        bf16x8 vb0 = *(const bf16x8*)(kvtb + dt * 1024 + l16);
        bf16x8 vb1 = *(const bf16x8*)(kvtb + (8 + dt) * 1024 + l16);
#pragma unroll
        for (int qs = 0; qs < 2; ++qs) {
          acc[qs][dt] = mfma16(pa[qs][0], vb0, acc[qs][dt]);
          acc[qs][dt] = mfma16(pa[qs][1], vb1, acc[qs][dt]);
        }
      }
      __builtin_amdgcn_s_setprio(0);

      // all waves done reading kv(s)/kvt(s); refill
      __builtin_amdgcn_s_barrier();
      asm volatile("" ::: "memory");
      if (s + 1 < nt) STAGE_KVT(s);            // tile(s+1) = s
      if (s + 2 < nt) STAGE_KV(s & 1, s + 1);  // tile(s+2) = s+1
    }

    // combine g-group partial sums, normalize, write out
#pragma unroll
    for (int qs = 0; qs < 2; ++qs) {
      lrun[qs] += __shfl_xor(lrun[qs], 16);
      lrun[qs] += __shfl_xor(lrun[qs], 32);
    }

    float* ob = out + ((size_t)b * TL + qt * 64 + 32 * w) * TE + h * TD;
#pragma unroll
    for (int qs = 0; qs < 2; ++qs) {
      const float inv = 1.f / lrun[qs];
      float ir[4];
#pragma unroll
      for (int r = 0; r < 4; ++r) ir[r] = __shfl(inv, g * 4 + r);
#pragma unroll
      for (int dt = 0; dt < 8; ++dt)
#pragma unroll
        for (int r = 0; r < 4; ++r)
          ob[(16 * qs + g * 4 + r) * TE + dt * 16 + q15] = acc[qs][dt][r] * ir[r];
    }

    __builtin_amdgcn_s_barrier();  // protect buffers before next segment
    asm volatile("" ::: "memory");
  }
}

// ---------------- fallback (v1-style, self-contained, no ws needed) ---------
__device__ __forceinline__ bf16x8 ld256s(const unsigned short* base, int row, int inrow) {
  const int off = (row * 256 + inrow) ^ ((row & 7) << 4);
  return *(const bf16x8*)((const char*)base + off);
}
__device__ __forceinline__ bf16x8 ld128s(const unsigned short* base, int row, int inrow) {
  const int off = (row * 128 + inrow) ^ ((row & 7) << 4);
  return *(const bf16x8*)((const char*)base + off);
}

__device__ __forceinline__ void stage_tile_fb(const float* __restrict__ src,
                                              unsigned short* kv, unsigned short* kvt,
                                              int t) {
  const int kr = (t >> 4) << 2;
  const int d0 = (t & 15) << 3;
  unsigned short c[4][8];
#pragma unroll
  for (int rr = 0; rr < 4; ++rr) {
    const float* p = src + (kr + rr) * TE + d0;
    const float4 a = *(const float4*)p;
    const float4 b = *(const float4*)(p + 4);
    c[rr][0] = f2bf(a.x); c[rr][1] = f2bf(a.y); c[rr][2] = f2bf(a.z); c[rr][3] = f2bf(a.w);
    c[rr][4] = f2bf(b.x); c[rr][5] = f2bf(b.y); c[rr][6] = f2bf(b.z); c[rr][7] = f2bf(b.w);
  }
#pragma unroll
  for (int rr = 0; rr < 4; ++rr) {
    const int r = kr + rr;
    u16x8 o = {c[rr][0], c[rr][1], c[rr][2], c[rr][3],
               c[rr][4], c[rr][5], c[rr][6], c[rr][7]};
    const int off = (r * 256 + d0 * 2) ^ ((r & 7) << 4);
    *(u16x8*)((char*)kv + off) = o;
  }
#pragma unroll
  for (int cc = 0; cc < 8; ++cc) {
    const int d = d0 + cc;
    u16x4 o = {c[0][cc], c[1][cc], c[2][cc], c[3][cc]};
    const int off = (d * 128 + kr * 2) ^ ((d & 7) << 4);
    *(u16x4*)((char*)kvt + off) = o;
  }
}

__global__ void __launch_bounds__(256)
evo_attn(const float* __restrict__ x, float* __restrict__ out) {
  __shared__ unsigned short kv[KB * TD];
  __shared__ unsigned short kvt[TD * KB];
  __shared__ unsigned short pl[4 * 16 * KB];

  const int t = threadIdx.x;
  const int lane = t & 63;
  const int w = t >> 6;
  const int g = lane >> 4;
  const int q15 = lane & 15;

  const int bh = blockIdx.x & 31;
  const int qt = 31 - (blockIdx.x >> 5);
  const int b = bh >> 4;
  const int h = bh & 15;
  const float* xb = x + (size_t)b * TL * TE + h * TD;
  const int q0 = qt * KB;

  stage_tile_fb(xb + (size_t)q0 * TE, kv, kvt, t);
  __syncthreads();

  bf16x8 qf[4];
#pragma unroll
  for (int c = 0; c < 4; ++c)
    qf[c] = ld256s(kv, 16 * w + q15, c * 64 + g * 16);

  f32x4 acc[8];
#pragma unroll
  for (int dt = 0; dt < 8; ++dt) acc[dt] = (f32x4){0.f, 0.f, 0.f, 0.f};
  float mrun = -1e30f;
  float lrun = 0.f;
  unsigned short* plw = pl + w * (16 * KB);

  for (int s = 0; s <= qt; ++s) {
    if (s > 0) {
      __syncthreads();
      stage_tile_fb(xb + (size_t)(s - 1) * KB * TE, kv, kvt, t);
      __syncthreads();
    }
    float sv[16];
#pragma unroll
    for (int kt2 = 0; kt2 < 4; ++kt2) {
      f32x4 st = (f32x4){0.f, 0.f, 0.f, 0.f};
#pragma unroll
      for (int c = 0; c < 4; ++c) {
        bf16x8 kf = ld256s(kv, kt2 * 16 + q15, c * 64 + g * 16);
        st = mfma16(kf, qf[c], st);
      }
#pragma unroll
      for (int r = 0; r < 4; ++r) sv[kt2 * 4 + r] = st[r] * SCALE_LOG2E;
    }
    if (s == 0) {
      const int qrel = 16 * w + q15;
#pragma unroll
      for (int kt2 = 0; kt2 < 4; ++kt2)
#pragma unroll
        for (int r = 0; r < 4; ++r)
          if (kt2 * 16 + g * 4 + r > qrel) sv[kt2 * 4 + r] = -1e30f;
    }
    float tmax = sv[0];
#pragma unroll
    for (int i = 1; i < 16; ++i) tmax = fmaxf(tmax, sv[i]);
    tmax = fmaxf(tmax, __shfl_xor(tmax, 16));
    tmax = fmaxf(tmax, __shfl_xor(tmax, 32));
    const float mnew = fmaxf(mrun, tmax);
    const float al = exp2f(mrun - mnew);
    mrun = mnew;
    float psum = 0.f;
    unsigned short pb[16];
#pragma unroll
    for (int i = 0; i < 16; ++i) {
      const float p = exp2f(sv[i] - mnew);
      psum += p;
      pb[i] = f2bf(p);
    }
    lrun = lrun * al + psum;
#pragma unroll
    for (int kt2 = 0; kt2 < 4; ++kt2) {
      u16x4 o = {pb[kt2 * 4], pb[kt2 * 4 + 1], pb[kt2 * 4 + 2], pb[kt2 * 4 + 3]};
      const int off = (q15 * 128 + kt2 * 32 + g * 8) ^ ((q15 & 7) << 4);
      *(u16x4*)((char*)plw + off) = o;
    }
    asm volatile("s_waitcnt lgkmcnt(0)" ::: "memory");
    float ar[4];
#pragma unroll
    for (int r = 0; r < 4; ++r) ar[r] = __shfl(al, g * 4 + r);
#pragma unroll
    for (int dt = 0; dt < 8; ++dt)
#pragma unroll
      for (int r = 0; r < 4; ++r) acc[dt][r] *= ar[r];
    bf16x8 pa0 = ld128s(plw, q15, g * 16);
    bf16x8 pa1 = ld128s(plw, q15, 64 + g * 16);
#pragma unroll
    for (int dt = 0; dt < 8; ++dt) {
      bf16x8 vb0 = ld128s(kvt, dt * 16 + q15, g * 16);
      bf16x8 vb1 = ld128s(kvt, dt * 16 + q15, 64 + g * 16);
      acc[dt] = mfma16(pa0, vb0, acc[dt]);
      acc[dt] = mfma16(pa1, vb1, acc[dt]);
    }
  }

  lrun += __shfl_xor(lrun, 16);
  lrun += __shfl_xor(lrun, 32);
  const float inv = 1.f / lrun;
  float ir[4];
#pragma unroll
  for (int r = 0; r < 4; ++r) ir[r] = __shfl(inv, g * 4 + r);
  float* ob = out + ((size_t)b * TL + q0 + 16 * w) * TE + h * TD;
#pragma unroll
  for (int dt = 0; dt < 8; ++dt)
#pragma unroll
    for (int r = 0; r < 4; ++r)
      ob[(g * 4 + r) * TE + dt * 16 + q15] = acc[dt][r] * ir[r];
}

extern "C" void kernel_launch(void* const* d_in, const int* in_sizes, int n_in,
                              void* d_out, int out_size, void* d_ws, size_t ws_size,
                              hipStream_t stream) {
  const float* x = (const float*)d_in[0];
  float* out = (float*)d_out;
  (void)in_sizes; (void)n_in; (void)out_size;
  if (ws_size >= (size_t)WS_NEED) {
    char* wsb = (char*)d_ws;
    prepack<<<dim3(1024), dim3(256), 0, stream>>>(x, wsb);
    evo_attn5<<<dim3(512), dim3(128), 0, stream>>>(wsb, out);
  } else {
    evo_attn<<<dim3(1024), dim3(256), 0, stream>>>(x, out);
  }
}